// Round 8
// baseline (1849.572 us; speedup 1.0000x reference)
//
#include <hip/hip_runtime.h>
#include <hip/hip_bf16.h>

#define NN 100000
#define EE 1600000
#define GG 512
#define DIN 78
#define DF 32
#define DOUT 128
#define BN_EPS 1e-5f

#define NBLK_NODE 3125      // NN / 32 (proj kernels)
#define NBLK_AGG 12500      // NN / 8  (agg kernel)

#define BSH 9               // 512 nodes per bucket
#define NBUCK 196           // ceil(100000 / 512)
#define SCB 256             // scatter blocks
#define EPB (EE / SCB)      // 6250 edges per scatter block

// ---------------------------------------------------------------- CSR build (bucketed)
__global__ __launch_bounds__(256) void k_bhist(const int* __restrict__ dst, int* __restrict__ hist_g) {
    __shared__ int hist[NBUCK];
    int tid = threadIdx.x, blk = blockIdx.x;
    if (tid < NBUCK) hist[tid] = 0;
    __syncthreads();
    int start = blk * EPB, end = start + EPB;
    for (int i = start + tid; i < end; i += 256) atomicAdd(&hist[dst[i] >> BSH], 1);
    __syncthreads();
    if (tid < NBUCK) hist_g[tid * SCB + blk] = hist[tid];
}

__global__ __launch_bounds__(256) void k_bscan(int* __restrict__ hist_g, int* __restrict__ bbase) {
    __shared__ int tot[256];
    int t = threadIdx.x;
    int total = 0;
    if (t < NBUCK)
        for (int blk = 0; blk < SCB; ++blk) total += hist_g[t * SCB + blk];
    tot[t] = (t < NBUCK) ? total : 0;
    __syncthreads();
    for (int off = 1; off < 256; off <<= 1) {
        int u = (t >= off) ? tot[t - off] : 0;
        __syncthreads();
        tot[t] += u;
        __syncthreads();
    }
    int excl = tot[t] - total;
    if (t < NBUCK) {
        bbase[t] = excl;
        int run = excl;
        for (int blk = 0; blk < SCB; ++blk) {
            int h = hist_g[t * SCB + blk];
            hist_g[t * SCB + blk] = run;
            run += h;
        }
    }
    if (t == 0) bbase[NBUCK] = EE;
}

__global__ __launch_bounds__(256) void k_bscatter(const int* __restrict__ src, const int* __restrict__ dst,
                                                  const int* __restrict__ hist_g, int* __restrict__ pairs) {
    __shared__ int base_l[NBUCK];
    __shared__ int cnt[NBUCK];
    int tid = threadIdx.x, blk = blockIdx.x;
    if (tid < NBUCK) { base_l[tid] = hist_g[tid * SCB + blk]; cnt[tid] = 0; }
    __syncthreads();
    int start = blk * EPB, end = start + EPB;
    for (int i = start + tid; i < end; i += 256) {
        int d = dst[i], s = src[i];
        int b = d >> BSH;
        int rk = atomicAdd(&cnt[b], 1);
        pairs[base_l[b] + rk] = s | ((d & 511) << 17);
    }
}

__global__ __launch_bounds__(256) void k_bfill(const int* __restrict__ pairs, const int* __restrict__ bbase,
                                               int* __restrict__ row_ptr, int* __restrict__ col) {
    __shared__ int cnt[512];
    __shared__ int excl[512];
    __shared__ int ps[256];
    int tid = threadIdx.x, b = blockIdx.x;
    int base = bbase[b];
    int cntb = bbase[b + 1] - base;
    int nbase = b << BSH;
    int nloc = NN - nbase; if (nloc > 512) nloc = 512;
    cnt[tid] = 0; cnt[tid + 256] = 0;
    __syncthreads();
    for (int i = tid; i < cntb; i += 256) atomicAdd(&cnt[(unsigned)pairs[base + i] >> 17], 1);
    __syncthreads();
    int a0 = cnt[2 * tid], a1 = cnt[2 * tid + 1];
    ps[tid] = a0 + a1;
    __syncthreads();
    for (int off = 1; off < 256; off <<= 1) {
        int u = (tid >= off) ? ps[tid - off] : 0;
        __syncthreads();
        ps[tid] += u;
        __syncthreads();
    }
    int pexcl = ps[tid] - (a0 + a1);
    excl[2 * tid] = pexcl;
    excl[2 * tid + 1] = pexcl + a0;
    __syncthreads();
    for (int i = tid; i < nloc; i += 256) row_ptr[nbase + i] = base + excl[i];
    if (b == 0 && tid == 0) row_ptr[NN] = EE;
    __syncthreads();
    for (int i = tid; i < cntb; i += 256) {
        int v = pairs[base + i];
        int dloc = (unsigned)v >> 17;
        int s = v & 0x1FFFF;
        int lp = atomicAdd(&excl[dloc], 1);
        col[base + lp] = s;
    }
}

// ---------------------------------------------------------------- layer kernels
// p = x @ w1  (layer 1, DIN=78, no BN).  32 nodes/block, single sync.
__global__ __launch_bounds__(256) void k_proj_first(const float* __restrict__ x,
                                                    const float* __restrict__ w1,
                                                    float* __restrict__ p) {
    __shared__ float w[DIN][DF];
    __shared__ float hx[32][DIN];
    int tid = threadIdx.x;
    for (int i = tid; i < DIN * DF; i += 256) w[i >> 5][i & 31] = w1[i];
    int base = blockIdx.x * 32;
    for (int i = tid; i < 32 * DIN; i += 256) hx[i / DIN][i % DIN] = x[base * DIN + i];
    __syncthreads();
    int j = tid & 31;
    #pragma unroll
    for (int it = 0; it < 4; ++it) {
        int rown = (tid >> 5) + 8 * it;
        float acc = 0.f;
        #pragma unroll
        for (int k = 0; k < DIN; ++k) acc += hx[rown][k] * w[k][j];
        p[(base + rown) * DF + j] = acc;
    }
}

// p = BN(r) @ w1  (hidden layers).  BN stats computed inline from raw sums.
__global__ __launch_bounds__(256) void k_proj_hidden(const float* __restrict__ r,
                                                     const float* __restrict__ w1_,
                                                     const float* __restrict__ statsL,
                                                     const float* __restrict__ gamma,
                                                     const float* __restrict__ beta,
                                                     float* __restrict__ p) {
    __shared__ float w[DF][DF];
    __shared__ float h[32][DF + 1];
    int tid = threadIdx.x;
    for (int i = tid; i < DF * DF; i += 256) w[i >> 5][i & 31] = w1_[i];
    int grp = tid >> 3, c = tid & 7;
    int node = blockIdx.x * 32 + grp;
    const float invN = 1.0f / (float)NN;
    float4 s1v = ((const float4*)statsL)[c];
    float4 s2v = ((const float4*)(statsL + DF))[c];
    float4 gv  = ((const float4*)gamma)[c];
    float4 bv  = ((const float4*)beta)[c];
    float4 rv  = ((const float4*)r)[node * 8 + c];
    float mux = s1v.x * invN, muy = s1v.y * invN, muz = s1v.z * invN, muw = s1v.w * invN;
    float ivx = rsqrtf(s2v.x * invN - mux * mux + BN_EPS);
    float ivy = rsqrtf(s2v.y * invN - muy * muy + BN_EPS);
    float ivz = rsqrtf(s2v.z * invN - muz * muz + BN_EPS);
    float ivw = rsqrtf(s2v.w * invN - muw * muw + BN_EPS);
    h[grp][4 * c + 0] = gv.x * (rv.x - mux) * ivx + bv.x;
    h[grp][4 * c + 1] = gv.y * (rv.y - muy) * ivy + bv.y;
    h[grp][4 * c + 2] = gv.z * (rv.z - muz) * ivz + bv.z;
    h[grp][4 * c + 3] = gv.w * (rv.w - muw) * ivw + bv.w;
    __syncthreads();
    int j = tid & 31;
    #pragma unroll
    for (int it = 0; it < 4; ++it) {
        int rown = (tid >> 5) + 8 * it;
        float acc = 0.f;
        #pragma unroll
        for (int k = 0; k < DF; ++k) acc += h[rown][k] * w[k][j];
        p[(blockIdx.x * 32 + rown) * DF + j] = acc;
    }
}

// agg: 8 nodes/block, 4 register-accumulating walkers per node (x float4 lanes),
// LDS combine (plain adds), then MLP-2 + relu + BN-sum atomics.
__global__ __launch_bounds__(256) void k_agg(const float* __restrict__ p,
                                             const int* __restrict__ row_ptr,
                                             const int* __restrict__ col,
                                             const float* __restrict__ b1,
                                             const float* __restrict__ w2_,
                                             const float* __restrict__ b2,
                                             float* __restrict__ r,
                                             float* __restrict__ statsL) {
    __shared__ float w[DF][DF];
    __shared__ float asum[8][4][DF];   // [node][walker][feat]
    __shared__ float a[8][DF + 1];
    __shared__ float red[4][2][DF];
    int tid = threadIdx.x;
    for (int i = tid; i < DF * DF; i += 256) w[i >> 5][i & 31] = w2_[i];
    int nl = tid >> 5;          // node-local 0..7
    int wk = (tid >> 3) & 3;    // walker 0..3
    int c  = tid & 7;           // float4 slice
    int base = blockIdx.x * 8;
    int node = base + nl;
    const float4* p4 = (const float4*)p;
    float4 acc;
    if (wk == 0) {
        float4 self = p4[node * 8 + c];
        float4 b1v = ((const float4*)b1)[c];
        acc.x = self.x + b1v.x; acc.y = self.y + b1v.y;
        acc.z = self.z + b1v.z; acc.w = self.w + b1v.w;
    } else {
        acc.x = acc.y = acc.z = acc.w = 0.f;
    }
    int e0 = row_ptr[node], e1 = row_ptr[node + 1];
    for (int e = e0 + wk; e < e1; e += 4) {
        int srcn = col[e];
        float4 v = p4[srcn * 8 + c];
        acc.x += v.x; acc.y += v.y; acc.z += v.z; acc.w += v.w;
    }
    ((float4*)&asum[nl][wk][4 * c])[0] = acc;
    __syncthreads();
    // combine walkers + relu: one thread per (node, feat)
    {
        int n2 = tid >> 5, k2 = tid & 31;
        float s = asum[n2][0][k2] + asum[n2][1][k2] + asum[n2][2][k2] + asum[n2][3][k2];
        a[n2][k2] = fmaxf(s, 0.f);
    }
    __syncthreads();
    int j = tid & 31;
    float b2j = b2[j];
    int rown = tid >> 5;
    float accm = b2j;
    #pragma unroll
    for (int k = 0; k < DF; ++k) accm += a[rown][k] * w[k][j];
    float rv = fmaxf(accm, 0.f);
    r[(base + rown) * DF + j] = rv;
    float s1 = rv, s2 = rv * rv;
    s1 += __shfl_down(s1, 32);
    s2 += __shfl_down(s2, 32);
    int wave = tid >> 6, lane = tid & 63;
    if (lane < 32) { red[wave][0][j] = s1; red[wave][1][j] = s2; }
    __syncthreads();
    if (tid < 32) {
        float t1 = red[0][0][j] + red[1][0][j] + red[2][0][j] + red[3][0][j];
        float t2 = red[0][1][j] + red[1][1][j] + red[2][1][j] + red[3][1][j];
        atomicAdd(&statsL[j], t1);
        atomicAdd(&statsL[DF + j], t2);
    }
}

// BN-apply (layer-5 sums) + global_add_pool; run-length accumulate.
__global__ __launch_bounds__(256) void k_pool(const float* __restrict__ r,
                                              const float* __restrict__ statsL,
                                              const float* __restrict__ gamma,
                                              const float* __restrict__ beta,
                                              const int* __restrict__ batch,
                                              float* __restrict__ pooled) {
    int t = blockIdx.x * 256 + threadIdx.x;
    int nodeBase = (t >> 5) * 8;
    if (nodeBase >= NN) return;
    int j = t & 31;
    const float invN = 1.0f / (float)NN;
    float mu = statsL[j] * invN;
    float inv = rsqrtf(statsL[DF + j] * invN - mu * mu + BN_EPS);
    float gj = gamma[j], bj = beta[j];
    float accp = 0.f;
    int curg = batch[nodeBase];
    #pragma unroll
    for (int k = 0; k < 8; ++k) {
        int n = nodeBase + k;
        int g = batch[n];
        float val = gj * (r[n * DF + j] - mu) * inv + bj;
        if (g != curg) { atomicAdd(&pooled[curg * DF + j], accp); accp = 0.f; curg = g; }
        accp += val;
    }
    atomicAdd(&pooled[curg * DF + j], accp);
}

__global__ __launch_bounds__(128) void k_fc(const float* __restrict__ pooled,
                                            const float* __restrict__ fc_w,
                                            const float* __restrict__ fc_b,
                                            float* __restrict__ out) {
    __shared__ float pl[DF];
    int g = blockIdx.x, j = threadIdx.x;
    if (j < DF) pl[j] = pooled[g * DF + j];
    __syncthreads();
    float acc = fc_b[j];
    #pragma unroll
    for (int k = 0; k < DF; ++k) acc += pl[k] * fc_w[k * DOUT + j];
    out[g * DOUT + j] = fmaxf(acc, 0.f);
}

// ---------------------------------------------------------------- host
extern "C" void kernel_launch(void* const* d_in, const int* in_sizes, int n_in,
                              void* d_out, int out_size, void* d_ws, size_t ws_size,
                              hipStream_t stream) {
    const float* x      = (const float*)d_in[0];
    const int*   eidx   = (const int*)d_in[1];
    const int*   batch  = (const int*)d_in[2];
    const float* w1_in  = (const float*)d_in[3];
    const float* b1_in  = (const float*)d_in[4];
    const float* w1_out = (const float*)d_in[5];
    const float* b1_out = (const float*)d_in[6];
    const float* wa     = (const float*)d_in[7];
    const float* ba     = (const float*)d_in[8];
    const float* wb     = (const float*)d_in[9];
    const float* bb     = (const float*)d_in[10];
    const float* gamma  = (const float*)d_in[11];
    const float* beta   = (const float*)d_in[12];
    const float* fc_w   = (const float*)d_in[13];
    const float* fc_b   = (const float*)d_in[14];
    float* out = (float*)d_out;

    const int* esrc = eidx;
    const int* edst = eidx + EE;

    // workspace carve-up
    float* W = (float*)d_ws;
    float* p       = W;                         // NN*DF floats (pairs overlay during CSR build)
    float* r       = p + (size_t)NN * DF;       // NN*DF
    float* pooled  = r + (size_t)NN * DF;       // GG*DF
    float* stats   = pooled + (size_t)GG * DF;  // 5*64 (s1|s2 per layer)
    int* row_ptr = (int*)(stats + 5 * 64);      // NN+1
    int* col     = row_ptr + (NN + 1);          // EE
    int* hist_g  = col + EE;                    // NBUCK*SCB
    int* bbase   = hist_g + NBUCK * SCB;        // NBUCK+1
    int* pairs   = (int*)p;                     // EE ints == 6.4 MB, overlays p

    // ---- CSR build (bucketed; same work every call) ----
    k_bhist<<<SCB, 256, 0, stream>>>(edst, hist_g);
    k_bscan<<<1, 256, 0, stream>>>(hist_g, bbase);
    k_bscatter<<<SCB, 256, 0, stream>>>(esrc, edst, hist_g, pairs);
    k_bfill<<<NBUCK, 256, 0, stream>>>(pairs, bbase, row_ptr, col);

    hipMemsetAsync(stats, 0, sizeof(float) * 5 * 64, stream);

    // ---- layer 1 ----
    k_proj_first<<<NBLK_NODE, 256, 0, stream>>>(x, w1_in, p);
    k_agg<<<NBLK_AGG, 256, 0, stream>>>(p, row_ptr, col, b1_in, w1_out, b1_out, r, stats);

    // ---- layers 2..5 ----
    for (int i = 1; i < 5; ++i) {
        const float* w1_ = wa + (size_t)(i - 1) * DF * DF;
        const float* b1_ = ba + (size_t)(i - 1) * DF;
        const float* w2_ = wb + (size_t)(i - 1) * DF * DF;
        const float* b2_ = bb + (size_t)(i - 1) * DF;
        const float* g_  = gamma + (size_t)(i - 1) * DF;
        const float* be_ = beta + (size_t)(i - 1) * DF;
        k_proj_hidden<<<NBLK_NODE, 256, 0, stream>>>(r, w1_, stats + (i - 1) * 64, g_, be_, p);
        k_agg<<<NBLK_AGG, 256, 0, stream>>>(p, row_ptr, col, b1_, w2_, b2_, r, stats + i * 64);
    }

    // ---- pool (+ BN of layer 5) and FC ----
    hipMemsetAsync(pooled, 0, sizeof(float) * GG * DF, stream);
    k_pool<<<((NN / 8) * 32 + 255) / 256, 256, 0, stream>>>(r, stats + 4 * 64, gamma + 4 * DF,
                                                            beta + 4 * DF, batch, pooled);
    k_fc<<<GG, 128, 0, stream>>>(pooled, fc_w, fc_b, out);
}

// Round 11
// 803.380 us; speedup vs baseline: 2.3022x; 2.3022x over previous
//
#include <hip/hip_runtime.h>
#include <hip/hip_bf16.h>

#define NN 100000
#define EE 1600000
#define GG 512
#define DIN 78
#define DF 32
#define DOUT 128
#define BN_EPS 1e-5f

#define NBLK_NODE 3125      // NN / 32

#define BSH 9               // 512 nodes per bucket
#define NBUCK 196           // ceil(100000 / 512)
#define SCB 256             // scatter blocks
#define EPB (EE / SCB)      // 6250 edges per scatter block

// ---------------------------------------------------------------- CSR build (bucketed)
__global__ __launch_bounds__(256) void k_bhist(const int* __restrict__ dst, int* __restrict__ hist_g) {
    __shared__ int hist[NBUCK];
    int tid = threadIdx.x, blk = blockIdx.x;
    if (tid < NBUCK) hist[tid] = 0;
    __syncthreads();
    int start = blk * EPB, end = start + EPB;
    for (int i = start + tid; i < end; i += 256) atomicAdd(&hist[dst[i] >> BSH], 1);
    __syncthreads();
    if (tid < NBUCK) hist_g[tid * SCB + blk] = hist[tid];
}

__global__ __launch_bounds__(256) void k_bscan(int* __restrict__ hist_g, int* __restrict__ bbase) {
    __shared__ int tot[256];
    int t = threadIdx.x;
    int total = 0;
    if (t < NBUCK)
        for (int blk = 0; blk < SCB; ++blk) total += hist_g[t * SCB + blk];
    tot[t] = (t < NBUCK) ? total : 0;
    __syncthreads();
    for (int off = 1; off < 256; off <<= 1) {
        int u = (t >= off) ? tot[t - off] : 0;
        __syncthreads();
        tot[t] += u;
        __syncthreads();
    }
    int excl = tot[t] - total;
    if (t < NBUCK) {
        bbase[t] = excl;
        int run = excl;
        for (int blk = 0; blk < SCB; ++blk) {
            int h = hist_g[t * SCB + blk];
            hist_g[t * SCB + blk] = run;
            run += h;
        }
    }
    if (t == 0) bbase[NBUCK] = EE;
}

__global__ __launch_bounds__(256) void k_bscatter(const int* __restrict__ src, const int* __restrict__ dst,
                                                  const int* __restrict__ hist_g, int* __restrict__ pairs) {
    __shared__ int base_l[NBUCK];
    __shared__ int cnt[NBUCK];
    int tid = threadIdx.x, blk = blockIdx.x;
    if (tid < NBUCK) { base_l[tid] = hist_g[tid * SCB + blk]; cnt[tid] = 0; }
    __syncthreads();
    int start = blk * EPB, end = start + EPB;
    for (int i = start + tid; i < end; i += 256) {
        int d = dst[i], s = src[i];
        int b = d >> BSH;
        int rk = atomicAdd(&cnt[b], 1);
        pairs[base_l[b] + rk] = s | ((d & 511) << 17);
    }
}

__global__ __launch_bounds__(256) void k_bfill(const int* __restrict__ pairs, const int* __restrict__ bbase,
                                               int* __restrict__ row_ptr, int* __restrict__ col) {
    __shared__ int cnt[512];
    __shared__ int excl[512];
    __shared__ int ps[256];
    int tid = threadIdx.x, b = blockIdx.x;
    int base = bbase[b];
    int cntb = bbase[b + 1] - base;
    int nbase = b << BSH;
    int nloc = NN - nbase; if (nloc > 512) nloc = 512;
    cnt[tid] = 0; cnt[tid + 256] = 0;
    __syncthreads();
    for (int i = tid; i < cntb; i += 256) atomicAdd(&cnt[(unsigned)pairs[base + i] >> 17], 1);
    __syncthreads();
    int a0 = cnt[2 * tid], a1 = cnt[2 * tid + 1];
    ps[tid] = a0 + a1;
    __syncthreads();
    for (int off = 1; off < 256; off <<= 1) {
        int u = (tid >= off) ? ps[tid - off] : 0;
        __syncthreads();
        ps[tid] += u;
        __syncthreads();
    }
    int pexcl = ps[tid] - (a0 + a1);
    excl[2 * tid] = pexcl;
    excl[2 * tid + 1] = pexcl + a0;
    __syncthreads();
    for (int i = tid; i < nloc; i += 256) row_ptr[nbase + i] = base + excl[i];
    if (b == 0 && tid == 0) row_ptr[NN] = EE;
    __syncthreads();
    for (int i = tid; i < cntb; i += 256) {
        int v = pairs[base + i];
        int dloc = (unsigned)v >> 17;
        int s = v & 0x1FFFF;
        int lp = atomicAdd(&excl[dloc], 1);
        col[base + lp] = s;
    }
}

// ---------------------------------------------------------------- layer kernels
// p = x @ w1  (layer 1, DIN=78, no BN).  32 nodes/block, single sync.
__global__ __launch_bounds__(256) void k_proj_first(const float* __restrict__ x,
                                                    const float* __restrict__ w1,
                                                    float* __restrict__ p) {
    __shared__ float w[DIN][DF];
    __shared__ float hx[32][DIN];
    int tid = threadIdx.x;
    for (int i = tid; i < DIN * DF; i += 256) w[i >> 5][i & 31] = w1[i];
    int base = blockIdx.x * 32;
    for (int i = tid; i < 32 * DIN; i += 256) hx[i / DIN][i % DIN] = x[base * DIN + i];
    __syncthreads();
    int j = tid & 31;
    #pragma unroll
    for (int it = 0; it < 4; ++it) {
        int rown = (tid >> 5) + 8 * it;
        float acc = 0.f;
        #pragma unroll
        for (int k = 0; k < DIN; ++k) acc += hx[rown][k] * w[k][j];
        p[(base + rown) * DF + j] = acc;
    }
}

// p = BN(r) @ w1  (hidden layers).  BN stats computed inline from raw sums.
__global__ __launch_bounds__(256) void k_proj_hidden(const float* __restrict__ r,
                                                     const float* __restrict__ w1_,
                                                     const float* __restrict__ statsL,
                                                     const float* __restrict__ gamma,
                                                     const float* __restrict__ beta,
                                                     float* __restrict__ p) {
    __shared__ float w[DF][DF];
    __shared__ float h[32][DF + 1];
    int tid = threadIdx.x;
    for (int i = tid; i < DF * DF; i += 256) w[i >> 5][i & 31] = w1_[i];
    int grp = tid >> 3, c = tid & 7;
    int node = blockIdx.x * 32 + grp;
    const float invN = 1.0f / (float)NN;
    float4 s1v = ((const float4*)statsL)[c];
    float4 s2v = ((const float4*)(statsL + DF))[c];
    float4 gv  = ((const float4*)gamma)[c];
    float4 bv  = ((const float4*)beta)[c];
    float4 rv  = ((const float4*)r)[node * 8 + c];
    float mux = s1v.x * invN, muy = s1v.y * invN, muz = s1v.z * invN, muw = s1v.w * invN;
    float ivx = rsqrtf(s2v.x * invN - mux * mux + BN_EPS);
    float ivy = rsqrtf(s2v.y * invN - muy * muy + BN_EPS);
    float ivz = rsqrtf(s2v.z * invN - muz * muz + BN_EPS);
    float ivw = rsqrtf(s2v.w * invN - muw * muw + BN_EPS);
    h[grp][4 * c + 0] = gv.x * (rv.x - mux) * ivx + bv.x;
    h[grp][4 * c + 1] = gv.y * (rv.y - muy) * ivy + bv.y;
    h[grp][4 * c + 2] = gv.z * (rv.z - muz) * ivz + bv.z;
    h[grp][4 * c + 3] = gv.w * (rv.w - muw) * ivw + bv.w;
    __syncthreads();
    int j = tid & 31;
    #pragma unroll
    for (int it = 0; it < 4; ++it) {
        int rown = (tid >> 5) + 8 * it;
        float acc = 0.f;
        #pragma unroll
        for (int k = 0; k < DF; ++k) acc += h[rown][k] * w[k][j];
        p[(blockIdx.x * 32 + rown) * DF + j] = acc;
    }
}

// agg: round-6 geometry (32 nodes/block, 8-lane group per node, register
// accumulate) + 4-way ILP in the edge walk (4 independent accumulators,
// 4 gathers in flight per group).  Then MLP-2 + relu + BN-sum atomics.
__global__ __launch_bounds__(256) void k_agg(const float* __restrict__ p,
                                             const int* __restrict__ row_ptr,
                                             const int* __restrict__ col,
                                             const float* __restrict__ b1,
                                             const float* __restrict__ w2_,
                                             const float* __restrict__ b2,
                                             float* __restrict__ r,
                                             float* __restrict__ statsL) {
    __shared__ float w[DF][DF];
    __shared__ float a[32][DF + 1];
    __shared__ float red[4][2][DF];
    int tid = threadIdx.x;
    for (int i = tid; i < DF * DF; i += 256) w[i >> 5][i & 31] = w2_[i];
    int grp = tid >> 3, c = tid & 7;
    int base = blockIdx.x * 32;
    int node = base + grp;
    const float4* p4 = (const float4*)p;
    float4 b1v = ((const float4*)b1)[c];
    float4 self = p4[node * 8 + c];
    float4 acc0, acc1, acc2, acc3;
    acc0.x = self.x + b1v.x; acc0.y = self.y + b1v.y;
    acc0.z = self.z + b1v.z; acc0.w = self.w + b1v.w;
    acc1.x = acc1.y = acc1.z = acc1.w = 0.f;
    acc2.x = acc2.y = acc2.z = acc2.w = 0.f;
    acc3.x = acc3.y = acc3.z = acc3.w = 0.f;
    int e0 = row_ptr[node], e1 = row_ptr[node + 1];
    int e = e0;
    for (; e + 4 <= e1; e += 4) {
        int s0 = col[e], s1 = col[e + 1], s2 = col[e + 2], s3 = col[e + 3];
        float4 v0 = p4[s0 * 8 + c];
        float4 v1 = p4[s1 * 8 + c];
        float4 v2 = p4[s2 * 8 + c];
        float4 v3 = p4[s3 * 8 + c];
        acc0.x += v0.x; acc0.y += v0.y; acc0.z += v0.z; acc0.w += v0.w;
        acc1.x += v1.x; acc1.y += v1.y; acc1.z += v1.z; acc1.w += v1.w;
        acc2.x += v2.x; acc2.y += v2.y; acc2.z += v2.z; acc2.w += v2.w;
        acc3.x += v3.x; acc3.y += v3.y; acc3.z += v3.z; acc3.w += v3.w;
    }
    for (; e < e1; ++e) {
        int s = col[e];
        float4 v = p4[s * 8 + c];
        acc0.x += v.x; acc0.y += v.y; acc0.z += v.z; acc0.w += v.w;
    }
    acc0.x += acc1.x + acc2.x + acc3.x;
    acc0.y += acc1.y + acc2.y + acc3.y;
    acc0.z += acc1.z + acc2.z + acc3.z;
    acc0.w += acc1.w + acc2.w + acc3.w;
    a[grp][4 * c + 0] = fmaxf(acc0.x, 0.f);
    a[grp][4 * c + 1] = fmaxf(acc0.y, 0.f);
    a[grp][4 * c + 2] = fmaxf(acc0.z, 0.f);
    a[grp][4 * c + 3] = fmaxf(acc0.w, 0.f);
    __syncthreads();
    int j = tid & 31;
    float b2j = b2[j];
    float s1 = 0.f, s2 = 0.f;
    #pragma unroll
    for (int it = 0; it < 4; ++it) {
        int rown = (tid >> 5) + 8 * it;
        float accm = b2j;
        #pragma unroll
        for (int k = 0; k < DF; ++k) accm += a[rown][k] * w[k][j];
        float rv = fmaxf(accm, 0.f);
        r[(base + rown) * DF + j] = rv;
        s1 += rv;
        s2 += rv * rv;
    }
    s1 += __shfl_down(s1, 32);
    s2 += __shfl_down(s2, 32);
    int wave = tid >> 6, lane = tid & 63;
    if (lane < 32) { red[wave][0][j] = s1; red[wave][1][j] = s2; }
    __syncthreads();
    if (tid < 32) {
        float t1 = red[0][0][j] + red[1][0][j] + red[2][0][j] + red[3][0][j];
        float t2 = red[0][1][j] + red[1][1][j] + red[2][1][j] + red[3][1][j];
        atomicAdd(&statsL[j], t1);
        atomicAdd(&statsL[DF + j], t2);
    }
}

// BN-apply (layer-5 sums) + global_add_pool; run-length accumulate.
__global__ __launch_bounds__(256) void k_pool(const float* __restrict__ r,
                                              const float* __restrict__ statsL,
                                              const float* __restrict__ gamma,
                                              const float* __restrict__ beta,
                                              const int* __restrict__ batch,
                                              float* __restrict__ pooled) {
    int t = blockIdx.x * 256 + threadIdx.x;
    int nodeBase = (t >> 5) * 8;
    if (nodeBase >= NN) return;
    int j = t & 31;
    const float invN = 1.0f / (float)NN;
    float mu = statsL[j] * invN;
    float inv = rsqrtf(statsL[DF + j] * invN - mu * mu + BN_EPS);
    float gj = gamma[j], bj = beta[j];
    float accp = 0.f;
    int curg = batch[nodeBase];
    #pragma unroll
    for (int k = 0; k < 8; ++k) {
        int n = nodeBase + k;
        int g = batch[n];
        float val = gj * (r[n * DF + j] - mu) * inv + bj;
        if (g != curg) { atomicAdd(&pooled[curg * DF + j], accp); accp = 0.f; curg = g; }
        accp += val;
    }
    atomicAdd(&pooled[curg * DF + j], accp);
}

__global__ __launch_bounds__(128) void k_fc(const float* __restrict__ pooled,
                                            const float* __restrict__ fc_w,
                                            const float* __restrict__ fc_b,
                                            float* __restrict__ out) {
    __shared__ float pl[DF];
    int g = blockIdx.x, j = threadIdx.x;
    if (j < DF) pl[j] = pooled[g * DF + j];
    __syncthreads();
    float acc = fc_b[j];
    #pragma unroll
    for (int k = 0; k < DF; ++k) acc += pl[k] * fc_w[k * DOUT + j];
    out[g * DOUT + j] = fmaxf(acc, 0.f);
}

// ---------------------------------------------------------------- host
extern "C" void kernel_launch(void* const* d_in, const int* in_sizes, int n_in,
                              void* d_out, int out_size, void* d_ws, size_t ws_size,
                              hipStream_t stream) {
    const float* x      = (const float*)d_in[0];
    const int*   eidx   = (const int*)d_in[1];
    const int*   batch  = (const int*)d_in[2];
    const float* w1_in  = (const float*)d_in[3];
    const float* b1_in  = (const float*)d_in[4];
    const float* w1_out = (const float*)d_in[5];
    const float* b1_out = (const float*)d_in[6];
    const float* wa     = (const float*)d_in[7];
    const float* ba     = (const float*)d_in[8];
    const float* wb     = (const float*)d_in[9];
    const float* bb     = (const float*)d_in[10];
    const float* gamma  = (const float*)d_in[11];
    const float* beta   = (const float*)d_in[12];
    const float* fc_w   = (const float*)d_in[13];
    const float* fc_b   = (const float*)d_in[14];
    float* out = (float*)d_out;

    const int* esrc = eidx;
    const int* edst = eidx + EE;

    // workspace carve-up
    float* W = (float*)d_ws;
    float* p       = W;                         // NN*DF floats (pairs overlay during CSR build)
    float* r       = p + (size_t)NN * DF;       // NN*DF
    float* pooled  = r + (size_t)NN * DF;       // GG*DF
    float* stats   = pooled + (size_t)GG * DF;  // 5*64 (s1|s2 per layer)
    int* row_ptr = (int*)(stats + 5 * 64);      // NN+1
    int* col     = row_ptr + (NN + 1);          // EE
    int* hist_g  = col + EE;                    // NBUCK*SCB
    int* bbase   = hist_g + NBUCK * SCB;        // NBUCK+1
    int* pairs   = (int*)p;                     // EE ints == 6.4 MB, overlays p

    // ---- CSR build (bucketed; same work every call) ----
    k_bhist<<<SCB, 256, 0, stream>>>(edst, hist_g);
    k_bscan<<<1, 256, 0, stream>>>(hist_g, bbase);
    k_bscatter<<<SCB, 256, 0, stream>>>(esrc, edst, hist_g, pairs);
    k_bfill<<<NBUCK, 256, 0, stream>>>(pairs, bbase, row_ptr, col);

    hipMemsetAsync(stats, 0, sizeof(float) * 5 * 64, stream);

    // ---- layer 1 ----
    k_proj_first<<<NBLK_NODE, 256, 0, stream>>>(x, w1_in, p);
    k_agg<<<NBLK_NODE, 256, 0, stream>>>(p, row_ptr, col, b1_in, w1_out, b1_out, r, stats);

    // ---- layers 2..5 ----
    for (int i = 1; i < 5; ++i) {
        const float* w1_ = wa + (size_t)(i - 1) * DF * DF;
        const float* b1_ = ba + (size_t)(i - 1) * DF;
        const float* w2_ = wb + (size_t)(i - 1) * DF * DF;
        const float* b2_ = bb + (size_t)(i - 1) * DF;
        const float* g_  = gamma + (size_t)(i - 1) * DF;
        const float* be_ = beta + (size_t)(i - 1) * DF;
        k_proj_hidden<<<NBLK_NODE, 256, 0, stream>>>(r, w1_, stats + (i - 1) * 64, g_, be_, p);
        k_agg<<<NBLK_NODE, 256, 0, stream>>>(p, row_ptr, col, b1_, w2_, b2_, r, stats + i * 64);
    }

    // ---- pool (+ BN of layer 5) and FC ----
    hipMemsetAsync(pooled, 0, sizeof(float) * GG * DF, stream);
    k_pool<<<((NN / 8) * 32 + 255) / 256, 256, 0, stream>>>(r, stats + 4 * 64, gamma + 4 * DF,
                                                            beta + 4 * DF, batch, pooled);
    k_fc<<<GG, 128, 0, stream>>>(pooled, fc_w, fc_b, out);
}

// Round 15
// 801.841 us; speedup vs baseline: 2.3067x; 1.0019x over previous
//
#include <hip/hip_runtime.h>
#include <hip/hip_bf16.h>
#include <hip/hip_fp16.h>

#define NN 100000
#define EE 1600000
#define GG 512
#define DIN 78
#define DF 32
#define DOUT 128
#define BN_EPS 1e-5f

#define NBLK_NODE 3125      // NN / 32

#define BSH 9               // 512 nodes per bucket
#define NBUCK 196           // ceil(100000 / 512)
#define SCB 256             // scatter blocks
#define EPB (EE / SCB)      // 6250 edges per scatter block

__device__ __forceinline__ unsigned short f2h(float f) {
    return __half_as_ushort(__float2half(f));
}
__device__ __forceinline__ float hlo(unsigned int v) {
    return __half2float(__ushort_as_half((unsigned short)(v & 0xFFFFu)));
}
__device__ __forceinline__ float hhi(unsigned int v) {
    return __half2float(__ushort_as_half((unsigned short)(v >> 16)));
}

// ---------------------------------------------------------------- CSR build (bucketed)
__global__ __launch_bounds__(256) void k_bhist(const int* __restrict__ dst, int* __restrict__ hist_g) {
    __shared__ int hist[NBUCK];
    int tid = threadIdx.x, blk = blockIdx.x;
    if (tid < NBUCK) hist[tid] = 0;
    __syncthreads();
    int start = blk * EPB, end = start + EPB;
    for (int i = start + tid; i < end; i += 256) atomicAdd(&hist[dst[i] >> BSH], 1);
    __syncthreads();
    if (tid < NBUCK) hist_g[tid * SCB + blk] = hist[tid];
}

__global__ __launch_bounds__(256) void k_bscan(int* __restrict__ hist_g, int* __restrict__ bbase) {
    __shared__ int tot[256];
    int t = threadIdx.x;
    int total = 0;
    if (t < NBUCK)
        for (int blk = 0; blk < SCB; ++blk) total += hist_g[t * SCB + blk];
    tot[t] = (t < NBUCK) ? total : 0;
    __syncthreads();
    for (int off = 1; off < 256; off <<= 1) {
        int u = (t >= off) ? tot[t - off] : 0;
        __syncthreads();
        tot[t] += u;
        __syncthreads();
    }
    int excl = tot[t] - total;
    if (t < NBUCK) {
        bbase[t] = excl;
        int run = excl;
        for (int blk = 0; blk < SCB; ++blk) {
            int h = hist_g[t * SCB + blk];
            hist_g[t * SCB + blk] = run;
            run += h;
        }
    }
    if (t == 0) bbase[NBUCK] = EE;
}

__global__ __launch_bounds__(256) void k_bscatter(const int* __restrict__ src, const int* __restrict__ dst,
                                                  const int* __restrict__ hist_g, int* __restrict__ pairs) {
    __shared__ int base_l[NBUCK];
    __shared__ int cnt[NBUCK];
    int tid = threadIdx.x, blk = blockIdx.x;
    if (tid < NBUCK) { base_l[tid] = hist_g[tid * SCB + blk]; cnt[tid] = 0; }
    __syncthreads();
    int start = blk * EPB, end = start + EPB;
    for (int i = start + tid; i < end; i += 256) {
        int d = dst[i], s = src[i];
        int b = d >> BSH;
        int rk = atomicAdd(&cnt[b], 1);
        pairs[base_l[b] + rk] = s | ((d & 511) << 17);
    }
}

__global__ __launch_bounds__(256) void k_bfill(const int* __restrict__ pairs, const int* __restrict__ bbase,
                                               int* __restrict__ row_ptr, int* __restrict__ col) {
    __shared__ int cnt[512];
    __shared__ int excl[512];
    __shared__ int ps[256];
    int tid = threadIdx.x, b = blockIdx.x;
    int base = bbase[b];
    int cntb = bbase[b + 1] - base;
    int nbase = b << BSH;
    int nloc = NN - nbase; if (nloc > 512) nloc = 512;
    cnt[tid] = 0; cnt[tid + 256] = 0;
    __syncthreads();
    for (int i = tid; i < cntb; i += 256) atomicAdd(&cnt[(unsigned)pairs[base + i] >> 17], 1);
    __syncthreads();
    int a0 = cnt[2 * tid], a1 = cnt[2 * tid + 1];
    ps[tid] = a0 + a1;
    __syncthreads();
    for (int off = 1; off < 256; off <<= 1) {
        int u = (tid >= off) ? ps[tid - off] : 0;
        __syncthreads();
        ps[tid] += u;
        __syncthreads();
    }
    int pexcl = ps[tid] - (a0 + a1);
    excl[2 * tid] = pexcl;
    excl[2 * tid + 1] = pexcl + a0;
    __syncthreads();
    for (int i = tid; i < nloc; i += 256) row_ptr[nbase + i] = base + excl[i];
    if (b == 0 && tid == 0) row_ptr[NN] = EE;
    __syncthreads();
    for (int i = tid; i < cntb; i += 256) {
        int v = pairs[base + i];
        int dloc = (unsigned)v >> 17;
        int s = v & 0x1FFFF;
        int lp = atomicAdd(&excl[dloc], 1);
        col[base + lp] = s;
    }
}

// ---------------------------------------------------------------- layer kernels
// p = x @ w1  (layer 1).  Writes f32 p and fp16 pb.
__global__ __launch_bounds__(256) void k_proj_first(const float* __restrict__ x,
                                                    const float* __restrict__ w1,
                                                    float* __restrict__ p,
                                                    unsigned short* __restrict__ pb) {
    __shared__ float w[DIN][DF];
    __shared__ float hx[32][DIN];
    int tid = threadIdx.x;
    for (int i = tid; i < DIN * DF; i += 256) w[i >> 5][i & 31] = w1[i];
    int base = blockIdx.x * 32;
    for (int i = tid; i < 32 * DIN; i += 256) hx[i / DIN][i % DIN] = x[base * DIN + i];
    __syncthreads();
    int j = tid & 31;
    #pragma unroll
    for (int it = 0; it < 4; ++it) {
        int rown = (tid >> 5) + 8 * it;
        float acc = 0.f;
        #pragma unroll
        for (int k = 0; k < DIN; ++k) acc += hx[rown][k] * w[k][j];
        p[(base + rown) * DF + j] = acc;
        pb[(base + rown) * DF + j] = f2h(acc);
    }
}

// p = BN(r) @ w1  (hidden layers).  Writes f32 p and fp16 pb.
__global__ __launch_bounds__(256) void k_proj_hidden(const float* __restrict__ r,
                                                     const float* __restrict__ w1_,
                                                     const float* __restrict__ statsL,
                                                     const float* __restrict__ gamma,
                                                     const float* __restrict__ beta,
                                                     float* __restrict__ p,
                                                     unsigned short* __restrict__ pb) {
    __shared__ float w[DF][DF];
    __shared__ float h[32][DF + 1];
    int tid = threadIdx.x;
    for (int i = tid; i < DF * DF; i += 256) w[i >> 5][i & 31] = w1_[i];
    int grp = tid >> 3, c = tid & 7;
    int node = blockIdx.x * 32 + grp;
    const float invN = 1.0f / (float)NN;
    float4 s1v = ((const float4*)statsL)[c];
    float4 s2v = ((const float4*)(statsL + DF))[c];
    float4 gv  = ((const float4*)gamma)[c];
    float4 bv  = ((const float4*)beta)[c];
    float4 rv  = ((const float4*)r)[node * 8 + c];
    float mux = s1v.x * invN, muy = s1v.y * invN, muz = s1v.z * invN, muw = s1v.w * invN;
    float ivx = rsqrtf(s2v.x * invN - mux * mux + BN_EPS);
    float ivy = rsqrtf(s2v.y * invN - muy * muy + BN_EPS);
    float ivz = rsqrtf(s2v.z * invN - muz * muz + BN_EPS);
    float ivw = rsqrtf(s2v.w * invN - muw * muw + BN_EPS);
    h[grp][4 * c + 0] = gv.x * (rv.x - mux) * ivx + bv.x;
    h[grp][4 * c + 1] = gv.y * (rv.y - muy) * ivy + bv.y;
    h[grp][4 * c + 2] = gv.z * (rv.z - muz) * ivz + bv.z;
    h[grp][4 * c + 3] = gv.w * (rv.w - muw) * ivw + bv.w;
    __syncthreads();
    int j = tid & 31;
    #pragma unroll
    for (int it = 0; it < 4; ++it) {
        int rown = (tid >> 5) + 8 * it;
        float acc = 0.f;
        #pragma unroll
        for (int k = 0; k < DF; ++k) acc += h[rown][k] * w[k][j];
        p[(blockIdx.x * 32 + rown) * DF + j] = acc;
        pb[(blockIdx.x * 32 + rown) * DF + j] = f2h(acc);
    }
}

// agg: round-6 geometry + 4-way ILP, gathers from fp16 pb (8 B/lane, 1 line/node).
// Self term from f32 p.  Then MLP-2 + relu + BN-sum atomics.
__global__ __launch_bounds__(256) void k_agg(const float* __restrict__ p,
                                             const unsigned short* __restrict__ pb,
                                             const int* __restrict__ row_ptr,
                                             const int* __restrict__ col,
                                             const float* __restrict__ b1,
                                             const float* __restrict__ w2_,
                                             const float* __restrict__ b2,
                                             float* __restrict__ r,
                                             float* __restrict__ statsL) {
    __shared__ float w[DF][DF];
    __shared__ float a[32][DF + 1];
    __shared__ float red[4][2][DF];
    int tid = threadIdx.x;
    for (int i = tid; i < DF * DF; i += 256) w[i >> 5][i & 31] = w2_[i];
    int grp = tid >> 3, c = tid & 7;
    int base = blockIdx.x * 32;
    int node = base + grp;
    const float4* p4 = (const float4*)p;
    const uint2* pb2 = (const uint2*)pb;   // 8 uint2 per node (64 B)
    float4 b1v = ((const float4*)b1)[c];
    float4 self = p4[node * 8 + c];
    float4 acc0, acc1, acc2, acc3;
    acc0.x = self.x + b1v.x; acc0.y = self.y + b1v.y;
    acc0.z = self.z + b1v.z; acc0.w = self.w + b1v.w;
    acc1.x = acc1.y = acc1.z = acc1.w = 0.f;
    acc2.x = acc2.y = acc2.z = acc2.w = 0.f;
    acc3.x = acc3.y = acc3.z = acc3.w = 0.f;
    int e0 = row_ptr[node], e1 = row_ptr[node + 1];
    int e = e0;
    for (; e + 4 <= e1; e += 4) {
        int s0 = col[e], s1 = col[e + 1], s2 = col[e + 2], s3 = col[e + 3];
        uint2 q0 = pb2[s0 * 8 + c];
        uint2 q1 = pb2[s1 * 8 + c];
        uint2 q2 = pb2[s2 * 8 + c];
        uint2 q3 = pb2[s3 * 8 + c];
        acc0.x += hlo(q0.x); acc0.y += hhi(q0.x); acc0.z += hlo(q0.y); acc0.w += hhi(q0.y);
        acc1.x += hlo(q1.x); acc1.y += hhi(q1.x); acc1.z += hlo(q1.y); acc1.w += hhi(q1.y);
        acc2.x += hlo(q2.x); acc2.y += hhi(q2.x); acc2.z += hlo(q2.y); acc2.w += hhi(q2.y);
        acc3.x += hlo(q3.x); acc3.y += hhi(q3.x); acc3.z += hlo(q3.y); acc3.w += hhi(q3.y);
    }
    for (; e < e1; ++e) {
        uint2 q = pb2[col[e] * 8 + c];
        acc0.x += hlo(q.x); acc0.y += hhi(q.x); acc0.z += hlo(q.y); acc0.w += hhi(q.y);
    }
    acc0.x += acc1.x + acc2.x + acc3.x;
    acc0.y += acc1.y + acc2.y + acc3.y;
    acc0.z += acc1.z + acc2.z + acc3.z;
    acc0.w += acc1.w + acc2.w + acc3.w;
    a[grp][4 * c + 0] = fmaxf(acc0.x, 0.f);
    a[grp][4 * c + 1] = fmaxf(acc0.y, 0.f);
    a[grp][4 * c + 2] = fmaxf(acc0.z, 0.f);
    a[grp][4 * c + 3] = fmaxf(acc0.w, 0.f);
    __syncthreads();
    int j = tid & 31;
    float b2j = b2[j];
    float s1 = 0.f, s2 = 0.f;
    #pragma unroll
    for (int it = 0; it < 4; ++it) {
        int rown = (tid >> 5) + 8 * it;
        float accm = b2j;
        #pragma unroll
        for (int k = 0; k < DF; ++k) accm += a[rown][k] * w[k][j];
        float rv = fmaxf(accm, 0.f);
        r[(base + rown) * DF + j] = rv;
        s1 += rv;
        s2 += rv * rv;
    }
    s1 += __shfl_down(s1, 32);
    s2 += __shfl_down(s2, 32);
    int wave = tid >> 6, lane = tid & 63;
    if (lane < 32) { red[wave][0][j] = s1; red[wave][1][j] = s2; }
    __syncthreads();
    if (tid < 32) {
        float t1 = red[0][0][j] + red[1][0][j] + red[2][0][j] + red[3][0][j];
        float t2 = red[0][1][j] + red[1][1][j] + red[2][1][j] + red[3][1][j];
        atomicAdd(&statsL[j], t1);
        atomicAdd(&statsL[DF + j], t2);
    }
}

// BN-apply (layer-5 sums) + global_add_pool; run-length accumulate.
__global__ __launch_bounds__(256) void k_pool(const float* __restrict__ r,
                                              const float* __restrict__ statsL,
                                              const float* __restrict__ gamma,
                                              const float* __restrict__ beta,
                                              const int* __restrict__ batch,
                                              float* __restrict__ pooled) {
    int t = blockIdx.x * 256 + threadIdx.x;
    int nodeBase = (t >> 5) * 8;
    if (nodeBase >= NN) return;
    int j = t & 31;
    const float invN = 1.0f / (float)NN;
    float mu = statsL[j] * invN;
    float inv = rsqrtf(statsL[DF + j] * invN - mu * mu + BN_EPS);
    float gj = gamma[j], bj = beta[j];
    float accp = 0.f;
    int curg = batch[nodeBase];
    #pragma unroll
    for (int k = 0; k < 8; ++k) {
        int n = nodeBase + k;
        int g = batch[n];
        float val = gj * (r[n * DF + j] - mu) * inv + bj;
        if (g != curg) { atomicAdd(&pooled[curg * DF + j], accp); accp = 0.f; curg = g; }
        accp += val;
    }
    atomicAdd(&pooled[curg * DF + j], accp);
}

__global__ __launch_bounds__(128) void k_fc(const float* __restrict__ pooled,
                                            const float* __restrict__ fc_w,
                                            const float* __restrict__ fc_b,
                                            float* __restrict__ out) {
    __shared__ float pl[DF];
    int g = blockIdx.x, j = threadIdx.x;
    if (j < DF) pl[j] = pooled[g * DF + j];
    __syncthreads();
    float acc = fc_b[j];
    #pragma unroll
    for (int k = 0; k < DF; ++k) acc += pl[k] * fc_w[k * DOUT + j];
    out[g * DOUT + j] = fmaxf(acc, 0.f);
}

// ---------------------------------------------------------------- host
extern "C" void kernel_launch(void* const* d_in, const int* in_sizes, int n_in,
                              void* d_out, int out_size, void* d_ws, size_t ws_size,
                              hipStream_t stream) {
    const float* x      = (const float*)d_in[0];
    const int*   eidx   = (const int*)d_in[1];
    const int*   batch  = (const int*)d_in[2];
    const float* w1_in  = (const float*)d_in[3];
    const float* b1_in  = (const float*)d_in[4];
    const float* w1_out = (const float*)d_in[5];
    const float* b1_out = (const float*)d_in[6];
    const float* wa     = (const float*)d_in[7];
    const float* ba     = (const float*)d_in[8];
    const float* wb     = (const float*)d_in[9];
    const float* bb     = (const float*)d_in[10];
    const float* gamma  = (const float*)d_in[11];
    const float* beta   = (const float*)d_in[12];
    const float* fc_w   = (const float*)d_in[13];
    const float* fc_b   = (const float*)d_in[14];
    float* out = (float*)d_out;

    const int* esrc = eidx;
    const int* edst = eidx + EE;

    // workspace carve-up
    float* W = (float*)d_ws;
    float* p       = W;                         // NN*DF floats (pairs overlay during CSR build)
    float* r       = p + (size_t)NN * DF;       // NN*DF
    float* pooled  = r + (size_t)NN * DF;       // GG*DF
    float* stats   = pooled + (size_t)GG * DF;  // 5*64 (s1|s2 per layer)
    int* row_ptr = (int*)(stats + 5 * 64);      // NN+1
    int* col     = row_ptr + (NN + 1);          // EE
    int* hist_g  = col + EE;                    // NBUCK*SCB
    int* bbase   = hist_g + NBUCK * SCB;        // NBUCK+1
    unsigned short* pb = (unsigned short*)(bbase + NBUCK + 1);  // NN*DF fp16 (6.4 MB)
    int* pairs   = (int*)p;                     // EE ints == 6.4 MB, overlays p

    // ---- CSR build (bucketed; same work every call) ----
    k_bhist<<<SCB, 256, 0, stream>>>(edst, hist_g);
    k_bscan<<<1, 256, 0, stream>>>(hist_g, bbase);
    k_bscatter<<<SCB, 256, 0, stream>>>(esrc, edst, hist_g, pairs);
    k_bfill<<<NBUCK, 256, 0, stream>>>(pairs, bbase, row_ptr, col);

    hipMemsetAsync(stats, 0, sizeof(float) * 5 * 64, stream);

    // ---- layer 1 ----
    k_proj_first<<<NBLK_NODE, 256, 0, stream>>>(x, w1_in, p, pb);
    k_agg<<<NBLK_NODE, 256, 0, stream>>>(p, pb, row_ptr, col, b1_in, w1_out, b1_out, r, stats);

    // ---- layers 2..5 ----
    for (int i = 1; i < 5; ++i) {
        const float* w1_ = wa + (size_t)(i - 1) * DF * DF;
        const float* b1_ = ba + (size_t)(i - 1) * DF;
        const float* w2_ = wb + (size_t)(i - 1) * DF * DF;
        const float* b2_ = bb + (size_t)(i - 1) * DF;
        const float* g_  = gamma + (size_t)(i - 1) * DF;
        const float* be_ = beta + (size_t)(i - 1) * DF;
        k_proj_hidden<<<NBLK_NODE, 256, 0, stream>>>(r, w1_, stats + (i - 1) * 64, g_, be_, p, pb);
        k_agg<<<NBLK_NODE, 256, 0, stream>>>(p, pb, row_ptr, col, b1_, w2_, b2_, r, stats + i * 64);
    }

    // ---- pool (+ BN of layer 5) and FC ----
    hipMemsetAsync(pooled, 0, sizeof(float) * GG * DF, stream);
    k_pool<<<((NN / 8) * 32 + 255) / 256, 256, 0, stream>>>(r, stats + 4 * 64, gamma + 4 * DF,
                                                            beta + 4 * DF, batch, pooled);
    k_fc<<<GG, 128, 0, stream>>>(pooled, fc_w, fc_b, out);
}